// Round 5
// baseline (224.924 us; speedup 1.0000x reference)
//
#include <hip/hip_runtime.h>
#include <hip/hip_fp16.h>

#define HH 28
#define WW 28
#define NPIX 784
#define BLOCK 832          // 13 waves; lanes 784..831 idle in compute
#define PSTRIDE 44         // slots/row (16B slots)
#define PROWS 36           // rows -4..31 (clamped center +-2 plus taps +-2)
#define TSLOTS (PROWS * PSTRIDE)   // 1584 slots * 16B = 25344 B per tile

// Round-5: slot-budget analysis shows VALU (8 cvt + 8 fma per tap) serializes
// with LDS instead of overlapping; per-slot stall residual ~6k cy is paid per
// barrier-slot. Fix: (1) v_fma_mix_f32 (f32*f16+f32 in ONE op, no cvts) via
// inline asm -- compiler provably didn't fuse (VALUBusy 34%); (2) 16 images
// per slot (two fp16 tiles) so the residual is amortized over 2x work;
// (3) coefs kept as e0[5]*e1[5] named scalars (10 regs) to fit VGPR cap 73.
__global__ __launch_bounds__(BLOCK, 7) void axs_89807766159734_kernel(
    const float* __restrict__ x, const float* __restrict__ pos2d,
    const float* __restrict__ weight, float* __restrict__ out,
    int nGroups8, int nSupers)
{
    __shared__ uint4 tiles[2][TSLOTS];     // 50688 B total, halos stay zero
    const int tid = threadIdx.x;
    const bool act = tid < NPIX;

    for (int i = tid; i < 2 * TSLOTS; i += BLOCK)
        ((uint4*)tiles)[i] = make_uint4(0u, 0u, 0u, 0u);

    // ---- separable coefficient vectors as named scalars ----
    float e00=0,e01=0,e02=0,e03=0,e04=0;   // row factors, relu(weight) folded in
    float e10=0,e11=0,e12=0,e13=0,e14=0;   // col factors
    int base = 0;
    if (act) {
        const float p0 = pos2d[2 * tid], p1 = pos2d[2 * tid + 1];
        const float sw = fmaxf(weight[tid], 0.0f);
        const float r0 = rintf(p0), r1 = rintf(p1);    // rintf == jnp.round
        const int i0 = (int)r0, i1 = (int)r1;
        const float f0 = r0 - p0, f1 = r1 - p1;        // d = f + off

        const float d0m2=f0-2.f, d0m1=f0-1.f, d0p1=f0+1.f, d0p2=f0+2.f;
        e00 = (i0-2>=0 && i0-2<HH) ? sw*__expf(-0.5f*d0m2*d0m2) : 0.f;
        e01 = (i0-1>=0 && i0-1<HH) ? sw*__expf(-0.5f*d0m1*d0m1) : 0.f;
        e02 = (i0  >=0 && i0  <HH) ? sw*__expf(-0.5f*f0  *f0  ) : 0.f;
        e03 = (i0+1>=0 && i0+1<HH) ? sw*__expf(-0.5f*d0p1*d0p1) : 0.f;
        e04 = (i0+2>=0 && i0+2<HH) ? sw*__expf(-0.5f*d0p2*d0p2) : 0.f;

        const float d1m2=f1-2.f, d1m1=f1-1.f, d1p1=f1+1.f, d1p2=f1+2.f;
        e10 = (i1-2>=0 && i1-2<WW) ? __expf(-0.5f*d1m2*d1m2) : 0.f;
        e11 = (i1-1>=0 && i1-1<WW) ? __expf(-0.5f*d1m1*d1m1) : 0.f;
        e12 = (i1  >=0 && i1  <WW) ? __expf(-0.5f*f1  *f1  ) : 0.f;
        e13 = (i1+1>=0 && i1+1<WW) ? __expf(-0.5f*d1p1*d1p1) : 0.f;
        e14 = (i1+2>=0 && i1+2<WW) ? __expf(-0.5f*d1p2*d1p2) : 0.f;

        const int a0c = min(max(i0, -2), HH + 1);      // addressing clamp only;
        const int a1c = min(max(i1, -2), WW + 1);      // clamped => coefs are 0
        base = ((a0c + 2) * PSTRIDE + (a1c + 2)) * 16; // (-2,-2) corner, bytes
    }
    const int myslot = (tid / WW + 4) * PSTRIDE + (tid % WW) + 4;

    // acc = cf(f32) * f16(low/high of pk u32) + acc   — single VALU op
#define MIXLO(acc, cf, pk) asm("v_fma_mix_f32 %0, %1, %2, %0 op_sel:[0,0,0] op_sel_hi:[0,1,0]" \
                               : "+v"(acc) : "v"(cf), "v"(pk))
#define MIXHI(acc, cf, pk) asm("v_fma_mix_f32 %0, %1, %2, %0 op_sel:[0,1,0] op_sel_hi:[0,1,0]" \
                               : "+v"(acc) : "v"(cf), "v"(pk))

    // ---- main loop: one super-group = 16 images (two 8-image tiles) ----
    int s = blockIdx.x;
    float va0=0,va1=0,va2=0,va3=0,va4=0,va5=0,va6=0,va7=0;   // group A = 2s
    float vb0=0,vb1=0,vb2=0,vb3=0,vb4=0,vb5=0,vb6=0,vb7=0;   // group B = 2s+1

#define LOADS(S) do {                                                      \
        const size_t bA = (size_t)(2*(S)) * 8u * NPIX;                     \
        va0 = x[bA + tid];          va1 = x[bA + NPIX + tid];              \
        va2 = x[bA + 2*NPIX + tid]; va3 = x[bA + 3*NPIX + tid];            \
        va4 = x[bA + 4*NPIX + tid]; va5 = x[bA + 5*NPIX + tid];            \
        va6 = x[bA + 6*NPIX + tid]; va7 = x[bA + 7*NPIX + tid];            \
        if (2*(S) + 1 < nGroups8) {                                        \
            const size_t bB = bA + 8u * NPIX;                              \
            vb0 = x[bB + tid];          vb1 = x[bB + NPIX + tid];          \
            vb2 = x[bB + 2*NPIX + tid]; vb3 = x[bB + 3*NPIX + tid];        \
            vb4 = x[bB + 4*NPIX + tid]; vb5 = x[bB + 5*NPIX + tid];        \
            vb6 = x[bB + 6*NPIX + tid]; vb7 = x[bB + 7*NPIX + tid];        \
        } } while (0)

    if (act && s < nSupers) LOADS(s);

    for (; s < nSupers; s += gridDim.x) {
        __syncthreads();                     // prev reads done (and zero-fill)
        if (act) {
            uint4 pa, pb;
            pa.x = __builtin_bit_cast(unsigned int, __floats2half2_rn(va0, va1));
            pa.y = __builtin_bit_cast(unsigned int, __floats2half2_rn(va2, va3));
            pa.z = __builtin_bit_cast(unsigned int, __floats2half2_rn(va4, va5));
            pa.w = __builtin_bit_cast(unsigned int, __floats2half2_rn(va6, va7));
            pb.x = __builtin_bit_cast(unsigned int, __floats2half2_rn(vb0, vb1));
            pb.y = __builtin_bit_cast(unsigned int, __floats2half2_rn(vb2, vb3));
            pb.z = __builtin_bit_cast(unsigned int, __floats2half2_rn(vb4, vb5));
            pb.w = __builtin_bit_cast(unsigned int, __floats2half2_rn(vb6, vb7));
            tiles[0][myslot] = pa;
            tiles[1][myslot] = pb;
        }
        __syncthreads();                     // staging visible

        const int sn = s + gridDim.x;        // prefetch next super during compute
        if (act && sn < nSupers) LOADS(sn);

        if (act) {
            float a0=0,a1=0,a2=0,a3=0,a4=0,a5=0,a6=0,a7=0;
            float b0=0,b1=0,b2=0,b3=0,b4=0,b5=0,b6=0,b7=0;
            const char* bpA = (const char*)(tiles[0]) + base;
            const char* bpB = (const char*)(tiles[1]) + base;
#define TAP(I, J, E0, E1) do {                                             \
            const float cf = (E0) * (E1);                                  \
            const uint4 ta = *(const uint4*)(bpA + ((I)*PSTRIDE+(J))*16);  \
            const uint4 tb = *(const uint4*)(bpB + ((I)*PSTRIDE+(J))*16);  \
            MIXLO(a0,cf,ta.x); MIXHI(a1,cf,ta.x);                          \
            MIXLO(a2,cf,ta.y); MIXHI(a3,cf,ta.y);                          \
            MIXLO(a4,cf,ta.z); MIXHI(a5,cf,ta.z);                          \
            MIXLO(a6,cf,ta.w); MIXHI(a7,cf,ta.w);                          \
            MIXLO(b0,cf,tb.x); MIXHI(b1,cf,tb.x);                          \
            MIXLO(b2,cf,tb.y); MIXHI(b3,cf,tb.y);                          \
            MIXLO(b4,cf,tb.z); MIXHI(b5,cf,tb.z);                          \
            MIXLO(b6,cf,tb.w); MIXHI(b7,cf,tb.w); } while (0)
            TAP(0,0,e00,e10); TAP(0,1,e00,e11); TAP(0,2,e00,e12); TAP(0,3,e00,e13); TAP(0,4,e00,e14);
            TAP(1,0,e01,e10); TAP(1,1,e01,e11); TAP(1,2,e01,e12); TAP(1,3,e01,e13); TAP(1,4,e01,e14);
            TAP(2,0,e02,e10); TAP(2,1,e02,e11); TAP(2,2,e02,e12); TAP(2,3,e02,e13); TAP(2,4,e02,e14);
            TAP(3,0,e03,e10); TAP(3,1,e03,e11); TAP(3,2,e03,e12); TAP(3,3,e03,e13); TAP(3,4,e03,e14);
            TAP(4,0,e04,e10); TAP(4,1,e04,e11); TAP(4,2,e04,e12); TAP(4,3,e04,e13); TAP(4,4,e04,e14);
#undef TAP
            const size_t bA = (size_t)(2*s) * 8u * NPIX;
            out[bA + tid]          = a0;  out[bA + NPIX + tid]   = a1;
            out[bA + 2*NPIX + tid] = a2;  out[bA + 3*NPIX + tid] = a3;
            out[bA + 4*NPIX + tid] = a4;  out[bA + 5*NPIX + tid] = a5;
            out[bA + 6*NPIX + tid] = a6;  out[bA + 7*NPIX + tid] = a7;
            if (2*s + 1 < nGroups8) {
                const size_t bB = bA + 8u * NPIX;
                out[bB + tid]          = b0;  out[bB + NPIX + tid]   = b1;
                out[bB + 2*NPIX + tid] = b2;  out[bB + 3*NPIX + tid] = b3;
                out[bB + 4*NPIX + tid] = b4;  out[bB + 5*NPIX + tid] = b5;
                out[bB + 6*NPIX + tid] = b6;  out[bB + 7*NPIX + tid] = b7;
            }
        }
    }
#undef LOADS
#undef MIXLO
#undef MIXHI
}

extern "C" void kernel_launch(void* const* d_in, const int* in_sizes, int n_in,
                              void* d_out, int out_size, void* d_ws, size_t ws_size,
                              hipStream_t stream) {
    const float* x      = (const float*)d_in[0];   // (B,1,28,28) fp32
    const float* pos2d  = (const float*)d_in[1];   // (28,28,2)   fp32
    const float* weight = (const float*)d_in[2];   // (28,28)     fp32
    float* out = (float*)d_out;

    const int B = in_sizes[0] / NPIX;              // 32768
    const int nGroups8 = B / 8;                    // 4096
    const int nSupers = (nGroups8 + 1) / 2;        // 2048 (16 images each)
    int blocks = nSupers < 1024 ? nSupers : 1024;  // 2 blocks/CU resident

    hipLaunchKernelGGL(axs_89807766159734_kernel, dim3(blocks), dim3(BLOCK), 0, stream,
                       x, pos2d, weight, out, nGroups8, nSupers);
}

// Round 6
// 182.787 us; speedup vs baseline: 1.2305x; 1.2305x over previous
//
#include <hip/hip_runtime.h>
#include <hip/hip_fp16.h>

#define HH 28
#define WW 28
#define NPIX 784
#define BLOCK 832          // 13 waves; lanes 784..831 idle in compute
#define PSTRIDE 44         // slots/row (16B slots)
#define PROWS 36           // rows -4..31 (clamped center +-2 plus taps +-2)
#define TSLOTS (PROWS * PSTRIDE)   // 1584 slots * 16B = 25344 B

// Round-6: exact round-3 structure (best measured, 64us/dispatch) with ONE
// change: the inner tap uses v_fma_mix_f32 (f32 coef * f16 pixel + f32 acc in
// a single VALU op) instead of 8x v_cvt + 8x fma. Round-5 proved the mix-op
// semantics but spilled (WRITE_SIZE 100->131 MB = scratch leak) from 2x
// register working set; this build keeps the r3 register budget (~50 VGPR).
__global__ __launch_bounds__(BLOCK, 7) void axs_89807766159734_kernel(
    const float* __restrict__ x, const float* __restrict__ pos2d,
    const float* __restrict__ weight, float* __restrict__ out,
    int nGroups)
{
    __shared__ uint4 img[TSLOTS];          // 25344 B, halo stays zero
    const int tid = threadIdx.x;
    const bool act = tid < NPIX;

    for (int s = tid; s < TSLOTS; s += BLOCK)
        img[s] = make_uint4(0u, 0u, 0u, 0u);

    // ---- 25 coefficients as named scalars (separable: e0[i]*e1[j]) ----
    float c00=0,c01=0,c02=0,c03=0,c04=0,
          c10=0,c11=0,c12=0,c13=0,c14=0,
          c20=0,c21=0,c22=0,c23=0,c24=0,
          c30=0,c31=0,c32=0,c33=0,c34=0,
          c40=0,c41=0,c42=0,c43=0,c44=0;
    int base = 0;
    if (act) {
        const float p0 = pos2d[2 * tid], p1 = pos2d[2 * tid + 1];
        const float sw = fmaxf(weight[tid], 0.0f);        // relu(weight) folded in
        const float r0 = rintf(p0), r1 = rintf(p1);       // rintf == jnp.round
        const int i0 = (int)r0, i1 = (int)r1;
        const float f0 = r0 - p0, f1 = r1 - p1;           // d = f + off

        const float d0m2 = f0 - 2.f, d0m1 = f0 - 1.f, d0p1 = f0 + 1.f, d0p2 = f0 + 2.f;
        const float e0m2 = (i0 - 2 >= 0 && i0 - 2 < HH) ? sw * __expf(-0.5f * d0m2 * d0m2) : 0.f;
        const float e0m1 = (i0 - 1 >= 0 && i0 - 1 < HH) ? sw * __expf(-0.5f * d0m1 * d0m1) : 0.f;
        const float e0z  = (i0     >= 0 && i0     < HH) ? sw * __expf(-0.5f * f0   * f0  ) : 0.f;
        const float e0p1 = (i0 + 1 >= 0 && i0 + 1 < HH) ? sw * __expf(-0.5f * d0p1 * d0p1) : 0.f;
        const float e0p2 = (i0 + 2 >= 0 && i0 + 2 < HH) ? sw * __expf(-0.5f * d0p2 * d0p2) : 0.f;

        const float d1m2 = f1 - 2.f, d1m1 = f1 - 1.f, d1p1 = f1 + 1.f, d1p2 = f1 + 2.f;
        const float e1m2 = (i1 - 2 >= 0 && i1 - 2 < WW) ? __expf(-0.5f * d1m2 * d1m2) : 0.f;
        const float e1m1 = (i1 - 1 >= 0 && i1 - 1 < WW) ? __expf(-0.5f * d1m1 * d1m1) : 0.f;
        const float e1z  = (i1     >= 0 && i1     < WW) ? __expf(-0.5f * f1   * f1  ) : 0.f;
        const float e1p1 = (i1 + 1 >= 0 && i1 + 1 < WW) ? __expf(-0.5f * d1p1 * d1p1) : 0.f;
        const float e1p2 = (i1 + 2 >= 0 && i1 + 2 < WW) ? __expf(-0.5f * d1p2 * d1p2) : 0.f;

        c00 = e0m2*e1m2; c01 = e0m2*e1m1; c02 = e0m2*e1z; c03 = e0m2*e1p1; c04 = e0m2*e1p2;
        c10 = e0m1*e1m2; c11 = e0m1*e1m1; c12 = e0m1*e1z; c13 = e0m1*e1p1; c14 = e0m1*e1p2;
        c20 = e0z *e1m2; c21 = e0z *e1m1; c22 = e0z *e1z; c23 = e0z *e1p1; c24 = e0z *e1p2;
        c30 = e0p1*e1m2; c31 = e0p1*e1m1; c32 = e0p1*e1z; c33 = e0p1*e1p1; c34 = e0p1*e1p2;
        c40 = e0p2*e1m2; c41 = e0p2*e1m1; c42 = e0p2*e1z; c43 = e0p2*e1p1; c44 = e0p2*e1p2;

        const int a0c = min(max(i0, -2), HH + 1);         // addressing clamp only;
        const int a1c = min(max(i1, -2), WW + 1);         // clamped => coefs all 0
        base = ((a0c + 2) * PSTRIDE + (a1c + 2)) * 16;    // (-2,-2) corner, bytes
    }
    const int myslot = (tid / WW + 4) * PSTRIDE + (tid % WW) + 4;

    // acc = cf(f32) * f16(low/high half of pk u32) + acc  — one VALU op
#define MIXLO(acc, cf, pk) asm("v_fma_mix_f32 %0, %1, %2, %0 op_sel:[0,0,0] op_sel_hi:[0,1,0]" \
                               : "+v"(acc) : "v"(cf), "v"(pk))
#define MIXHI(acc, cf, pk) asm("v_fma_mix_f32 %0, %1, %2, %0 op_sel:[0,1,0] op_sel_hi:[0,1,0]" \
                               : "+v"(acc) : "v"(cf), "v"(pk))

    // ---- main loop: groups of 8 images ----
    int g = blockIdx.x;
    float v0=0,v1=0,v2=0,v3=0,v4=0,v5=0,v6=0,v7=0;
    if (act && g < nGroups) {
        const size_t b = (size_t)g * 8u * NPIX;
        v0 = x[b + tid];            v1 = x[b + NPIX + tid];
        v2 = x[b + 2*NPIX + tid];   v3 = x[b + 3*NPIX + tid];
        v4 = x[b + 4*NPIX + tid];   v5 = x[b + 5*NPIX + tid];
        v6 = x[b + 6*NPIX + tid];   v7 = x[b + 7*NPIX + tid];
    }

    for (; g < nGroups; g += gridDim.x) {
        __syncthreads();                               // prev compute done (and init)
        if (act) {
            uint4 pk;
            pk.x = __builtin_bit_cast(unsigned int, __floats2half2_rn(v0, v1));
            pk.y = __builtin_bit_cast(unsigned int, __floats2half2_rn(v2, v3));
            pk.z = __builtin_bit_cast(unsigned int, __floats2half2_rn(v4, v5));
            pk.w = __builtin_bit_cast(unsigned int, __floats2half2_rn(v6, v7));
            img[myslot] = pk;                          // ds_write_b128
        }
        __syncthreads();                               // staging visible

        // prefetch next group's 8 floats while computing from LDS
        const int gn = g + gridDim.x;
        if (act && gn < nGroups) {
            const size_t nb = (size_t)gn * 8u * NPIX;
            v0 = x[nb + tid];            v1 = x[nb + NPIX + tid];
            v2 = x[nb + 2*NPIX + tid];   v3 = x[nb + 3*NPIX + tid];
            v4 = x[nb + 4*NPIX + tid];   v5 = x[nb + 5*NPIX + tid];
            v6 = x[nb + 6*NPIX + tid];   v7 = x[nb + 7*NPIX + tid];
        }

        if (act) {
            float a0=0,a1=0,a2=0,a3=0,a4=0,a5=0,a6=0,a7=0;
            const char* bp = (const char*)img + base;
#define TAP(I, J, C) do {                                                    \
            const uint4 tv = *(const uint4*)(bp + ((I) * PSTRIDE + (J)) * 16); \
            MIXLO(a0, C, tv.x);  MIXHI(a1, C, tv.x);                         \
            MIXLO(a2, C, tv.y);  MIXHI(a3, C, tv.y);                         \
            MIXLO(a4, C, tv.z);  MIXHI(a5, C, tv.z);                         \
            MIXLO(a6, C, tv.w);  MIXHI(a7, C, tv.w); } while (0)
            TAP(0,0,c00); TAP(0,1,c01); TAP(0,2,c02); TAP(0,3,c03); TAP(0,4,c04);
            TAP(1,0,c10); TAP(1,1,c11); TAP(1,2,c12); TAP(1,3,c13); TAP(1,4,c14);
            TAP(2,0,c20); TAP(2,1,c21); TAP(2,2,c22); TAP(2,3,c23); TAP(2,4,c24);
            TAP(3,0,c30); TAP(3,1,c31); TAP(3,2,c32); TAP(3,3,c33); TAP(3,4,c34);
            TAP(4,0,c40); TAP(4,1,c41); TAP(4,2,c42); TAP(4,3,c43); TAP(4,4,c44);
#undef TAP
            const size_t b = (size_t)g * 8u * NPIX;
            out[b + tid]          = a0;  out[b + NPIX + tid]   = a1;
            out[b + 2*NPIX + tid] = a2;  out[b + 3*NPIX + tid] = a3;
            out[b + 4*NPIX + tid] = a4;  out[b + 5*NPIX + tid] = a5;
            out[b + 6*NPIX + tid] = a6;  out[b + 7*NPIX + tid] = a7;
        }
    }
#undef MIXLO
#undef MIXHI
}

extern "C" void kernel_launch(void* const* d_in, const int* in_sizes, int n_in,
                              void* d_out, int out_size, void* d_ws, size_t ws_size,
                              hipStream_t stream) {
    const float* x      = (const float*)d_in[0];   // (B,1,28,28) fp32
    const float* pos2d  = (const float*)d_in[1];   // (28,28,2)   fp32
    const float* weight = (const float*)d_in[2];   // (28,28)     fp32
    float* out = (float*)d_out;

    const int B = in_sizes[0] / NPIX;              // 32768
    const int nGroups = B / 8;                     // 4096
    int blocks = nGroups < 1024 ? nGroups : 1024;  // 2 blocks/CU resident (26 waves)

    hipLaunchKernelGGL(axs_89807766159734_kernel, dim3(blocks), dim3(BLOCK), 0, stream,
                       x, pos2d, weight, out, nGroups);
}